// Round 1
// baseline (542.883 us; speedup 1.0000x reference)
//
#include <hip/hip_runtime.h>

// Problem constants
#define P_TOTAL   32768      // 8*64*64 patches
#define C_DIM     64         // patch dim / channels
#define N_ATOMS   512
#define K_SP      5
#define HW_DIM    4096       // 64*64
#define OUT_ZDL   2097152    // 8*64*64*64
#define OUT_LOSS  2097152
#define OUT_COEFF 2097153
#define COEFF_N   16777216   // 512*32768

// ---------------- zero the loss + coeffs region ----------------
__global__ void zero_tail(float* __restrict__ out) {
    // region: [OUT_LOSS, OUT_LOSS + 1 + COEFF_N) = 16777217 floats
    // byte offset of OUT_LOSS = 8388608, 16B aligned.
    float4* base = reinterpret_cast<float4*>(out + OUT_LOSS);
    const unsigned n4 = 4194304;  // 16777216/4
    unsigned stride = gridDim.x * blockDim.x;
    for (unsigned i = blockIdx.x * blockDim.x + threadIdx.x; i < n4; i += stride)
        base[i] = float4{0.f, 0.f, 0.f, 0.f};
    if (blockIdx.x == 0 && threadIdx.x == 0)
        out[OUT_LOSS + 16777216] = 0.f;  // last scalar of region
}

// ---------------- prep: G = D^T D + eps I (f64), Dt = D^T (f32) ----------------
__global__ void prep_kernel(const float* __restrict__ D,
                            double* __restrict__ G,
                            float* __restrict__ Dt) {
    int tid = blockIdx.x * blockDim.x + threadIdx.x;  // 1024*256 = 262144
    int i = tid >> 9;         // row atom
    int j = tid & 511;        // col atom (consecutive -> coalesced)
    double s = 0.0;
    #pragma unroll
    for (int m = 0; m < 64; ++m)
        s += (double)D[m * 512 + i] * (double)D[m * 512 + j];
    if (i == j) s += 1e-5;
    G[(size_t)i * 512 + j] = s;
    if (tid < N_ATOMS * C_DIM) {
        int n = tid >> 6, m = tid & 63;
        Dt[n * 64 + m] = D[m * 512 + n];
    }
}

// ---------------- OMP: one wave (64 lanes) per patch ----------------
__launch_bounds__(256)
__global__ void omp_kernel(const float* __restrict__ ze,
                           const float* __restrict__ D,
                           const double* __restrict__ G,
                           const float* __restrict__ Dt,
                           float* __restrict__ out) {
    __shared__ float sp[4][64];
    const int wave = threadIdx.x >> 6;
    const int lane = threadIdx.x & 63;
    const int p    = blockIdx.x * 4 + wave;
    const int b    = p >> 12;
    const int hw   = p & 4095;

    // patch element c = lane:  z_e[b, c, h, w]
    const float pe = ze[(size_t)(b * 64 + lane) * 4096 + hw];
    sp[wave][lane] = pe;
    __syncthreads();

    // h_bar: each lane owns atoms n = j*64 + lane, j = 0..7
    double hb[8];
    #pragma unroll
    for (int j = 0; j < 8; ++j) hb[j] = 0.0;
    for (int c = 0; c < 64; ++c) {
        const double pc = (double)sp[wave][c];
        const float* Drow = D + c * 512 + lane;
        #pragma unroll
        for (int j = 0; j < 8; ++j)
            hb[j] += pc * (double)Drow[j * 64];
    }

    double h[8];
    #pragma unroll
    for (int j = 0; j < 8; ++j) h[j] = hb[j];

    unsigned mask = 0;       // per-lane: which of my 8 atoms are active
    int    a[5];
    double rhs[5];
    double x[5];

    #pragma unroll
    for (int k = 0; k < K_SP; ++k) {
        // ---- local argmax of |h| (skip masked), lowest-n tie-break ----
        double bv = -1.0; int bn = 0x7fffffff;
        #pragma unroll
        for (int j = 0; j < 8; ++j) {
            double av = fabs(h[j]);
            bool ok = !((mask >> j) & 1u);
            int n = j * 64 + lane;
            if (ok && (av > bv || (av == bv && n < bn))) { bv = av; bn = n; }
        }
        // ---- wave argmax reduce ----
        #pragma unroll
        for (int off = 32; off > 0; off >>= 1) {
            double ov = __shfl_xor(bv, off);
            int    on = __shfl_xor(bn, off);
            if (ov > bv || (ov == bv && on < bn)) { bv = ov; bn = on; }
        }
        a[k] = bn;
        // broadcast h_bar[bn] from owner lane (static-index select, then shfl)
        {
            const int src = bn & 63, jj = bn >> 6;
            double v = 0.0;
            #pragma unroll
            for (int j = 0; j < 8; ++j) if (j == jj) v = hb[j];
            rhs[k] = __shfl(v, src);
            if (lane == src) mask |= (1u << jj);
        }

        // ---- solve (k+1)x(k+1) Gram system, replicated on all lanes ----
        double T[5][5], y[5];
        #pragma unroll
        for (int i = 0; i <= k; ++i) {
            #pragma unroll
            for (int j2 = 0; j2 <= k; ++j2)
                T[i][j2] = G[(size_t)a[i] * 512 + a[j2]];
            y[i] = rhs[i];
        }
        #pragma unroll
        for (int col = 0; col <= k; ++col) {
            double inv = 1.0 / T[col][col];
            #pragma unroll
            for (int r = col + 1; r <= k; ++r) {
                double f = T[r][col] * inv;
                #pragma unroll
                for (int cc = col; cc <= k; ++cc)
                    T[r][cc] -= f * T[col][cc];
                y[r] -= f * y[col];
            }
        }
        #pragma unroll
        for (int r = k; r >= 0; --r) {
            double s = y[r];
            #pragma unroll
            for (int cc = r + 1; cc <= k; ++cc) s -= T[r][cc] * x[cc];
            x[r] = s / T[r][r];
        }

        // ---- residual correlation update (skip dead final update) ----
        if (k < K_SP - 1) {
            #pragma unroll
            for (int j = 0; j < 8; ++j) {
                double s = hb[j];
                #pragma unroll
                for (int i = 0; i <= k; ++i)
                    s -= x[i] * G[(size_t)a[i] * 512 + j * 64 + lane];
                h[j] = s;
            }
        }
    }

    // ---- scatter coeffs.T: out[OUT_COEFF + n*32768 + p] ----
    if (lane == 0) {
        #pragma unroll
        for (int i = 0; i < K_SP; ++i)
            out[(size_t)OUT_COEFF + (size_t)a[i] * 32768 + p] = (float)x[i];
    }

    // ---- recon, z_dl_st, loss ----
    double rc = 0.0;
    #pragma unroll
    for (int i = 0; i < K_SP; ++i)
        rc += x[i] * (double)Dt[(size_t)a[i] * 64 + lane];
    const float zd = (float)rc;
    const float t  = zd - pe;          // matches z_e + stopgrad(z_dl - z_e)
    out[(size_t)(b * 64 + lane) * 4096 + hw] = pe + t;

    const float df = zd - pe;
    double sq = (double)df * (double)df;
    #pragma unroll
    for (int off = 32; off > 0; off >>= 1)
        sq += __shfl_xor(sq, off);
    if (lane == 0)
        atomicAdd(out + OUT_LOSS, (float)(sq * (1.25 / 2097152.0)));
}

extern "C" void kernel_launch(void* const* d_in, const int* in_sizes, int n_in,
                              void* d_out, int out_size, void* d_ws, size_t ws_size,
                              hipStream_t stream) {
    const float* ze = (const float*)d_in[0];   // (8,64,64,64) f32
    const float* D  = (const float*)d_in[1];   // (64,512) f32, unit-norm cols
    float* out = (float*)d_out;

    double* G  = (double*)d_ws;                                  // 512*512*8 = 2 MB
    float*  Dt = (float*)((char*)d_ws + (size_t)512 * 512 * 8);  // 512*64*4 = 128 KB

    zero_tail<<<2048, 256, 0, stream>>>(out);
    prep_kernel<<<1024, 256, 0, stream>>>(D, G, Dt);
    omp_kernel<<<P_TOTAL / 4, 256, 0, stream>>>(ze, D, G, Dt, out);
}